// Round 1
// baseline (536.115 us; speedup 1.0000x reference)
//
#include <hip/hip_runtime.h>

// ---------------------------------------------------------------------------
// SelfAttention: out = softmax((x@Wk+bk) @ (x@Wq+bq)^T) @ (x@Wv+bv)
// B=4, N=2048, E=A=1024, fp32 in/out.
// Strategy: bf16x2 split-precision MFMA GEMMs (3-term) for projections and
// scores (softmax tie-sensitivity demands ~fp32 scores), single-bf16 for
// attn@v. All GEMMs NT layout (contiguous K for both operands).
// ---------------------------------------------------------------------------

typedef __attribute__((ext_vector_type(8))) short short8;     // 8 bf16 = 4 VGPRs
typedef __attribute__((ext_vector_type(4))) float floatx4;

#define TILE 128
#define BK 32
#define LDSS 40   // LDS row stride in elements (32 + 8 pad; 80B keeps 16B align)

static __device__ __forceinline__ unsigned short f2bf(float f) {
    unsigned int u = __float_as_uint(f);
    u += 0x7FFFu + ((u >> 16) & 1u);   // round-to-nearest-even
    return (unsigned short)(u >> 16);
}
static __device__ __forceinline__ float bf2f(unsigned short h) {
    return __uint_as_float(((unsigned int)h) << 16);
}

// ---------------------------------------------------------------------------
// split fp32 -> bf16 hi + bf16 lo (elementwise, n % 4 == 0)
// ---------------------------------------------------------------------------
__global__ void split_f32(const float* __restrict__ src,
                          unsigned short* __restrict__ hi,
                          unsigned short* __restrict__ lo, int n) {
    int i = (blockIdx.x * blockDim.x + threadIdx.x) * 4;
    if (i >= n) return;
    float4 f = *(const float4*)(src + i);
    float v[4] = {f.x, f.y, f.z, f.w};
    ushort4 h, l;
    unsigned short hh[4], ll[4];
#pragma unroll
    for (int j = 0; j < 4; ++j) {
        hh[j] = f2bf(v[j]);
        ll[j] = f2bf(v[j] - bf2f(hh[j]));
    }
    h = make_ushort4(hh[0], hh[1], hh[2], hh[3]);
    l = make_ushort4(ll[0], ll[1], ll[2], ll[3]);
    *(ushort4*)(hi + i) = h;
    *(ushort4*)(lo + i) = l;
}

// ---------------------------------------------------------------------------
// W [R][C] fp32 -> W^T [C][R] as bf16 hi/lo (for NT GEMM B-operand)
// ---------------------------------------------------------------------------
__global__ void splitT_w(const float* __restrict__ W,
                         unsigned short* __restrict__ Th,
                         unsigned short* __restrict__ Tl, int R, int C) {
    __shared__ float tile[32][33];
    int tx = threadIdx.x & 31, ty = threadIdx.x >> 5;   // 32 x 8
    int c0 = blockIdx.x * 32, r0 = blockIdx.y * 32;
#pragma unroll
    for (int j = 0; j < 32; j += 8)
        tile[ty + j][tx] = W[(long long)(r0 + ty + j) * C + c0 + tx];
    __syncthreads();
#pragma unroll
    for (int j = 0; j < 32; j += 8) {
        float v = tile[tx][ty + j];                      // = W[r0+tx][c0+ty+j]
        long long idx = (long long)(c0 + ty + j) * R + r0 + tx;
        unsigned short h = f2bf(v);
        Th[idx] = h;
        Tl[idx] = f2bf(v - bf2f(h));
    }
}

// ---------------------------------------------------------------------------
// bf16 transpose: src [z][R][C] -> dst [z][C][R]
// ---------------------------------------------------------------------------
__global__ void transpose_bf(const unsigned short* __restrict__ src,
                             unsigned short* __restrict__ dst, int R, int C) {
    __shared__ unsigned short tile[32][33];
    long long zs = (long long)blockIdx.z * R * C;
    int tx = threadIdx.x & 31, ty = threadIdx.x >> 5;
    int c0 = blockIdx.x * 32, r0 = blockIdx.y * 32;
#pragma unroll
    for (int j = 0; j < 32; j += 8)
        tile[ty + j][tx] = src[zs + (long long)(r0 + ty + j) * C + c0 + tx];
    __syncthreads();
#pragma unroll
    for (int j = 0; j < 32; j += 8)
        dst[zs + (long long)(c0 + ty + j) * R + r0 + tx] = tile[tx][ty + j];
}

// ---------------------------------------------------------------------------
// NT GEMM: C[M,N] = A[M,K] * B[N,K]^T (+bias[col]); bf16 inputs, fp32 acc.
// SPLIT: A = Ah+Al, B = Bh+Bl, 3-term product (drops lo*lo).
// mode 0: store fp32 into Cf; mode 1: store bf16 hi/lo into Chi/Clo;
// mode 2: store bf16 into Chi.
// Dims must be multiples of TILE (M,N) and BK (K).  grid.z = batch.
// ---------------------------------------------------------------------------
template <bool SPLIT>
__global__ __launch_bounds__(256)
void gemm_nt(const unsigned short* __restrict__ Ah,
             const unsigned short* __restrict__ Al,
             const unsigned short* __restrict__ Bh,
             const unsigned short* __restrict__ Bl,
             const float* __restrict__ bias,
             float* __restrict__ Cf,
             unsigned short* __restrict__ Chi,
             unsigned short* __restrict__ Clo,
             int mode, int M, int N, int K,
             long long sA, long long sB, long long sC) {
    __shared__ unsigned short smem[(SPLIT ? 4 : 2) * TILE * LDSS];
    unsigned short* As_h = smem;
    unsigned short* Bs_h = smem + TILE * LDSS;
    unsigned short* As_l = SPLIT ? smem + 2 * TILE * LDSS : smem;
    unsigned short* Bs_l = SPLIT ? smem + 3 * TILE * LDSS : smem;

    const int tid = threadIdx.x;
    const int lane = tid & 63;
    const int wave = tid >> 6;
    const int quad = lane >> 4;
    const int l15 = lane & 15;
    const int wm = (wave & 1) * 64;
    const int wn = (wave >> 1) * 64;

    const long long zA = (long long)blockIdx.z * sA;
    const long long zB = (long long)blockIdx.z * sB;
    const long long zC = (long long)blockIdx.z * sC;
    const int m0 = blockIdx.y * TILE;
    const int n0 = blockIdx.x * TILE;

    // staging: 256 threads x 32B = 8KB = one 128x32 bf16 tile per array
    const int srow = tid >> 1;          // 0..127
    const int shalf = (tid & 1) * 16;   // element offset 0 or 16
    const unsigned int lds_off = srow * LDSS + shalf;

    floatx4 zero = {0.f, 0.f, 0.f, 0.f};
    floatx4 acc[4][4];
#pragma unroll
    for (int i = 0; i < 4; ++i)
#pragma unroll
        for (int j = 0; j < 4; ++j) acc[i][j] = zero;

    const long long arow = zA + (long long)(m0 + srow) * K + shalf;
    const long long brow = zB + (long long)(n0 + srow) * K + shalf;

    for (int k0 = 0; k0 < K; k0 += BK) {
        __syncthreads();
        {
            const unsigned short* ga = Ah + arow + k0;
            const unsigned short* gb = Bh + brow + k0;
            *(uint4*)&As_h[lds_off]     = *(const uint4*)(ga);
            *(uint4*)&As_h[lds_off + 8] = *(const uint4*)(ga + 8);
            *(uint4*)&Bs_h[lds_off]     = *(const uint4*)(gb);
            *(uint4*)&Bs_h[lds_off + 8] = *(const uint4*)(gb + 8);
            if (SPLIT) {
                const unsigned short* gal = Al + arow + k0;
                const unsigned short* gbl = Bl + brow + k0;
                *(uint4*)&As_l[lds_off]     = *(const uint4*)(gal);
                *(uint4*)&As_l[lds_off + 8] = *(const uint4*)(gal + 8);
                *(uint4*)&Bs_l[lds_off]     = *(const uint4*)(gbl);
                *(uint4*)&Bs_l[lds_off + 8] = *(const uint4*)(gbl + 8);
            }
        }
        __syncthreads();

        short8 a_h[4], b_h[4], a_l[4], b_l[4];
#pragma unroll
        for (int mi = 0; mi < 4; ++mi) {
            int r = wm + mi * 16 + l15;
            a_h[mi] = *(const short8*)&As_h[r * LDSS + quad * 8];
            if (SPLIT) a_l[mi] = *(const short8*)&As_l[r * LDSS + quad * 8];
        }
#pragma unroll
        for (int ni = 0; ni < 4; ++ni) {
            int r = wn + ni * 16 + l15;
            b_h[ni] = *(const short8*)&Bs_h[r * LDSS + quad * 8];
            if (SPLIT) b_l[ni] = *(const short8*)&Bs_l[r * LDSS + quad * 8];
        }
#pragma unroll
        for (int mi = 0; mi < 4; ++mi)
#pragma unroll
            for (int ni = 0; ni < 4; ++ni) {
                acc[mi][ni] = __builtin_amdgcn_mfma_f32_16x16x32_bf16(
                    a_h[mi], b_h[ni], acc[mi][ni], 0, 0, 0);
                if (SPLIT) {
                    acc[mi][ni] = __builtin_amdgcn_mfma_f32_16x16x32_bf16(
                        a_h[mi], b_l[ni], acc[mi][ni], 0, 0, 0);
                    acc[mi][ni] = __builtin_amdgcn_mfma_f32_16x16x32_bf16(
                        a_l[mi], b_h[ni], acc[mi][ni], 0, 0, 0);
                }
            }
    }

    // epilogue: C/D layout col=lane&15, row=quad*4+reg  [verified m89/m91]
#pragma unroll
    for (int mi = 0; mi < 4; ++mi)
#pragma unroll
        for (int ni = 0; ni < 4; ++ni) {
            int colg = n0 + wn + ni * 16 + l15;
            float bv = bias ? bias[colg] : 0.f;
#pragma unroll
            for (int r = 0; r < 4; ++r) {
                int rowg = m0 + wm + mi * 16 + quad * 4 + r;
                float v = acc[mi][ni][r] + bv;
                long long idx = zC + (long long)rowg * N + colg;
                if (mode == 0) {
                    Cf[idx] = v;
                } else if (mode == 1) {
                    unsigned short h = f2bf(v);
                    Chi[idx] = h;
                    Clo[idx] = f2bf(v - bf2f(h));
                } else {
                    Chi[idx] = f2bf(v);
                }
            }
        }
}

// ---------------------------------------------------------------------------
// row softmax: S [rows][cols] fp32 -> P bf16.  One block per row, cols=2048.
// ---------------------------------------------------------------------------
__global__ __launch_bounds__(256)
void softmax_rows(const float* __restrict__ S, unsigned short* __restrict__ P,
                  int cols) {
    __shared__ float red_m[4];
    __shared__ float red_s[4];
    const long long row = blockIdx.x;
    const float* s = S + row * cols;
    unsigned short* p = P + row * cols;
    const int tid = threadIdx.x;
    const int lane = tid & 63;
    const int wave = tid >> 6;

    float4 v0 = *(const float4*)(s + tid * 8);
    float4 v1 = *(const float4*)(s + tid * 8 + 4);
    float vals[8] = {v0.x, v0.y, v0.z, v0.w, v1.x, v1.y, v1.z, v1.w};

    float m = vals[0];
#pragma unroll
    for (int i = 1; i < 8; ++i) m = fmaxf(m, vals[i]);
#pragma unroll
    for (int off = 32; off >= 1; off >>= 1) m = fmaxf(m, __shfl_xor(m, off));
    if (lane == 0) red_m[wave] = m;
    __syncthreads();
    m = fmaxf(fmaxf(red_m[0], red_m[1]), fmaxf(red_m[2], red_m[3]));

    float e[8];
    float sum = 0.f;
#pragma unroll
    for (int i = 0; i < 8; ++i) {
        e[i] = __expf(vals[i] - m);
        sum += e[i];
    }
#pragma unroll
    for (int off = 32; off >= 1; off >>= 1) sum += __shfl_xor(sum, off);
    if (lane == 0) red_s[wave] = sum;
    __syncthreads();
    sum = red_s[0] + red_s[1] + red_s[2] + red_s[3];
    float inv = 1.0f / sum;

    unsigned short ob[8];
#pragma unroll
    for (int i = 0; i < 8; ++i) ob[i] = f2bf(e[i] * inv);
    *(ushort4*)(p + tid * 8)     = make_ushort4(ob[0], ob[1], ob[2], ob[3]);
    *(ushort4*)(p + tid * 8 + 4) = make_ushort4(ob[4], ob[5], ob[6], ob[7]);
}

// ---------------------------------------------------------------------------
extern "C" void kernel_launch(void* const* d_in, const int* in_sizes, int n_in,
                              void* d_out, int out_size, void* d_ws,
                              size_t ws_size, hipStream_t stream) {
    const float* x  = (const float*)d_in[0];
    const float* Wk = (const float*)d_in[1];
    const float* bk = (const float*)d_in[2];
    const float* Wq = (const float*)d_in[3];
    const float* bq = (const float*)d_in[4];
    const float* Wv = (const float*)d_in[5];
    const float* bv = (const float*)d_in[6];
    float* out = (float*)d_out;

    const int Bb = 4, Ns = 2048, E = 1024, Aa = 1024;
    const int M = Bb * Ns;  // 8192

    char* p = (char*)d_ws;
    auto alloc = [&](size_t bytes) {
        char* r = p;
        p += (bytes + 255) & ~(size_t)255;
        return r;
    };
    const size_t MA = (size_t)M * Aa;          // 8.39M elems
    unsigned short* xh = (unsigned short*)alloc(MA * 2);
    unsigned short* xl = (unsigned short*)alloc(MA * 2);
    unsigned short* Wth[3], *Wtl[3];
    for (int i = 0; i < 3; ++i) {
        Wth[i] = (unsigned short*)alloc((size_t)E * Aa * 2);
        Wtl[i] = (unsigned short*)alloc((size_t)E * Aa * 2);
    }
    unsigned short* kh = (unsigned short*)alloc(MA * 2);
    unsigned short* kl = (unsigned short*)alloc(MA * 2);
    unsigned short* qh = (unsigned short*)alloc(MA * 2);
    unsigned short* ql = (unsigned short*)alloc(MA * 2);
    unsigned short* vbf = (unsigned short*)alloc(MA * 2);
    unsigned short* vT  = (unsigned short*)alloc(MA * 2);
    float* scores = (float*)alloc((size_t)Bb * Ns * Ns * 4);
    // attn (bf16, 33.5MB) overlays the dead x_hi/x_lo region (33.5MB)
    unsigned short* attn = xh;

    // 1. split x, W (W transposed so B-operand has contiguous K)
    split_f32<<<(int)(MA / 4 / 256), 256, 0, stream>>>(x, xh, xl, (int)MA);
    splitT_w<<<dim3(Aa / 32, E / 32), 256, 0, stream>>>(Wk, Wth[0], Wtl[0], E, Aa);
    splitT_w<<<dim3(Aa / 32, E / 32), 256, 0, stream>>>(Wq, Wth[1], Wtl[1], E, Aa);
    splitT_w<<<dim3(Aa / 32, E / 32), 256, 0, stream>>>(Wv, Wth[2], Wtl[2], E, Aa);

    // 2. projections (split input, split output for k/q, single bf16 for v)
    dim3 g1(Aa / TILE, M / TILE, 1);
    gemm_nt<true><<<g1, 256, 0, stream>>>(xh, xl, Wth[0], Wtl[0], bk, nullptr,
                                          kh, kl, 1, M, Aa, E, 0, 0, 0);
    gemm_nt<true><<<g1, 256, 0, stream>>>(xh, xl, Wth[1], Wtl[1], bq, nullptr,
                                          qh, ql, 1, M, Aa, E, 0, 0, 0);
    gemm_nt<true><<<g1, 256, 0, stream>>>(xh, xl, Wth[2], Wtl[2], bv, nullptr,
                                          vbf, nullptr, 2, M, Aa, E, 0, 0, 0);

    // 3. scores[b,n,m] = k[b,n,:] . q[b,m,:]   (batched NT, fp32 out)
    dim3 g2(Ns / TILE, Ns / TILE, Bb);
    gemm_nt<true><<<g2, 256, 0, stream>>>(
        kh, kl, qh, ql, nullptr, scores, nullptr, nullptr, 0, Ns, Ns, Aa,
        (long long)Ns * Aa, (long long)Ns * Aa, (long long)Ns * Ns);

    // 4. softmax rows -> bf16 attn
    softmax_rows<<<M, 256, 0, stream>>>(scores, attn, Ns);

    // 5. v -> v^T (so attn@v is NT with contiguous K=m)
    transpose_bf<<<dim3(Aa / 32, Ns / 32, Bb), 256, 0, stream>>>(vbf, vT, Ns, Aa);

    // 6. out[b,n,a] = sum_m attn[b,n,m] * vT[b,a,m]
    dim3 g3(Aa / TILE, Ns / TILE, Bb);
    gemm_nt<false><<<g3, 256, 0, stream>>>(
        attn, nullptr, vT, nullptr, nullptr, out, nullptr, nullptr, 0, Ns, Aa,
        Ns, (long long)Ns * Ns, (long long)Aa * Ns, (long long)Ns * Aa);
}

// Round 2
// 471.541 us; speedup vs baseline: 1.1369x; 1.1369x over previous
//
#include <hip/hip_runtime.h>

// ---------------------------------------------------------------------------
// SelfAttention: out = softmax((x@Wk+bk) @ (x@Wq+bq)^T) @ (x@Wv+bv)
// B=4, N=2048, E=A=1024, fp32 in/out.
// bf16x2 split-precision MFMA GEMMs (3-term) for k/q projections and scores;
// single-bf16 for v projection and attn@v. NT layout everywhere.
// R2: global_load_lds(width=16) staging + XOR bank swizzle; v-proj 1-term.
// ---------------------------------------------------------------------------

typedef __attribute__((ext_vector_type(8))) short short8;     // 8 bf16 = 4 VGPRs
typedef __attribute__((ext_vector_type(4))) float floatx4;

#define TILE 128
#define BK 32

static __device__ __forceinline__ unsigned short f2bf(float f) {
    unsigned int u = __float_as_uint(f);
    u += 0x7FFFu + ((u >> 16) & 1u);   // round-to-nearest-even
    return (unsigned short)(u >> 16);
}
static __device__ __forceinline__ float bf2f(unsigned short h) {
    return __uint_as_float(((unsigned int)h) << 16);
}

// async global->LDS, 16B per lane; LDS dst = wave-uniform base + lane*16
static __device__ __forceinline__ void gll16(const unsigned short* g,
                                             unsigned short* l) {
    __builtin_amdgcn_global_load_lds(
        (__attribute__((address_space(1))) void*)(g),
        (__attribute__((address_space(3))) void*)(l), 16, 0, 0);
}

// ---------------------------------------------------------------------------
// split fp32 -> bf16 hi + bf16 lo (elementwise, n % 4 == 0)
// ---------------------------------------------------------------------------
__global__ void split_f32(const float* __restrict__ src,
                          unsigned short* __restrict__ hi,
                          unsigned short* __restrict__ lo, int n) {
    int i = (blockIdx.x * blockDim.x + threadIdx.x) * 4;
    if (i >= n) return;
    float4 f = *(const float4*)(src + i);
    float v[4] = {f.x, f.y, f.z, f.w};
    unsigned short hh[4], ll[4];
#pragma unroll
    for (int j = 0; j < 4; ++j) {
        hh[j] = f2bf(v[j]);
        ll[j] = f2bf(v[j] - bf2f(hh[j]));
    }
    *(ushort4*)(hi + i) = make_ushort4(hh[0], hh[1], hh[2], hh[3]);
    *(ushort4*)(lo + i) = make_ushort4(ll[0], ll[1], ll[2], ll[3]);
}

// ---------------------------------------------------------------------------
// W [R][C] fp32 -> W^T [C][R] as bf16 hi/lo (for NT GEMM B-operand)
// ---------------------------------------------------------------------------
__global__ void splitT_w(const float* __restrict__ W,
                         unsigned short* __restrict__ Th,
                         unsigned short* __restrict__ Tl, int R, int C) {
    __shared__ float tile[32][33];
    int tx = threadIdx.x & 31, ty = threadIdx.x >> 5;   // 32 x 8
    int c0 = blockIdx.x * 32, r0 = blockIdx.y * 32;
#pragma unroll
    for (int j = 0; j < 32; j += 8)
        tile[ty + j][tx] = W[(long long)(r0 + ty + j) * C + c0 + tx];
    __syncthreads();
#pragma unroll
    for (int j = 0; j < 32; j += 8) {
        float v = tile[tx][ty + j];                      // = W[r0+tx][c0+ty+j]
        long long idx = (long long)(c0 + ty + j) * R + r0 + tx;
        unsigned short h = f2bf(v);
        Th[idx] = h;
        Tl[idx] = f2bf(v - bf2f(h));
    }
}

// ---------------------------------------------------------------------------
// bf16 transpose: src [z][R][C] -> dst [z][C][R]
// ---------------------------------------------------------------------------
__global__ void transpose_bf(const unsigned short* __restrict__ src,
                             unsigned short* __restrict__ dst, int R, int C) {
    __shared__ unsigned short tile[32][33];
    long long zs = (long long)blockIdx.z * R * C;
    int tx = threadIdx.x & 31, ty = threadIdx.x >> 5;
    int c0 = blockIdx.x * 32, r0 = blockIdx.y * 32;
#pragma unroll
    for (int j = 0; j < 32; j += 8)
        tile[ty + j][tx] = src[zs + (long long)(r0 + ty + j) * C + c0 + tx];
    __syncthreads();
#pragma unroll
    for (int j = 0; j < 32; j += 8)
        dst[zs + (long long)(c0 + ty + j) * R + r0 + tx] = tile[tx][ty + j];
}

// ---------------------------------------------------------------------------
// NT GEMM: C[M,N] = A[M,K] * B[N,K]^T (+bias[col]); bf16 inputs, fp32 acc.
// SPLIT: A = Ah+Al, B = Bh+Bl, 3-term product (drops lo*lo).
// mode 0: store fp32 into Cf; mode 1: store bf16 hi/lo into Chi/Clo;
// mode 2: store bf16 into Chi.
// LDS: unpadded [row][32] tiles (global_load_lds requirement); bank conflicts
// broken by XOR chunk swizzle: chunk position p holds global chunk
// p ^ ((row>>1)&3) -- 16 lanes of a quad then span all 32 banks (2-way=free).
// ---------------------------------------------------------------------------
template <bool SPLIT>
__global__ __launch_bounds__(256)
void gemm_nt(const unsigned short* __restrict__ Ah,
             const unsigned short* __restrict__ Al,
             const unsigned short* __restrict__ Bh,
             const unsigned short* __restrict__ Bl,
             const float* __restrict__ bias,
             float* __restrict__ Cf,
             unsigned short* __restrict__ Chi,
             unsigned short* __restrict__ Clo,
             int mode, int M, int N, int K,
             long long sA, long long sB, long long sC) {
    __shared__ unsigned short smem[(SPLIT ? 4 : 2) * TILE * BK];
    unsigned short* As_h = smem;
    unsigned short* Bs_h = smem + TILE * BK;
    unsigned short* As_l = SPLIT ? smem + 2 * TILE * BK : smem;
    unsigned short* Bs_l = SPLIT ? smem + 3 * TILE * BK : smem;

    const int tid = threadIdx.x;
    const int lane = tid & 63;
    const int wave = tid >> 6;
    const int quad = lane >> 4;
    const int l15 = lane & 15;
    const int wm = (wave & 1) * 64;
    const int wn = (wave >> 1) * 64;

    const long long zA = (long long)blockIdx.z * sA;
    const long long zB = (long long)blockIdx.z * sB;
    const long long zC = (long long)blockIdx.z * sC;
    const int m0 = blockIdx.y * TILE;
    const int n0 = blockIdx.x * TILE;

    // --- staging addresses ---------------------------------------------------
    // wave w stages rows [32w, 32w+32) of A and B, 2 insts of 16 rows each.
    // lane i covers row (i>>2), global chunk c = (i&3) ^ ((i>>3)&3)  [swizzle]
    const int srow = wave * 32 + (lane >> 2);
    const int schunk8 = (((lane & 3) ^ ((lane >> 3) & 3)) << 3);
    const long long aoff0 = zA + (long long)(m0 + srow) * K + schunk8;
    const long long boff0 = zB + (long long)(n0 + srow) * K + schunk8;
    const long long aoff1 = aoff0 + 16LL * K;
    const long long boff1 = boff0 + 16LL * K;
    unsigned short* lA0 = As_h + (wave * 32) * BK;
    unsigned short* lA1 = lA0 + 16 * BK;
    unsigned short* lB0 = Bs_h + (wave * 32) * BK;
    unsigned short* lB1 = lB0 + 16 * BK;
    unsigned short* lA0l = As_l + (wave * 32) * BK;
    unsigned short* lA1l = lA0l + 16 * BK;
    unsigned short* lB0l = Bs_l + (wave * 32) * BK;
    unsigned short* lB1l = lB0l + 16 * BK;

    floatx4 zero = {0.f, 0.f, 0.f, 0.f};
    floatx4 acc[4][4];
#pragma unroll
    for (int i = 0; i < 4; ++i)
#pragma unroll
        for (int j = 0; j < 4; ++j) acc[i][j] = zero;

    for (int k0 = 0; k0 < K; k0 += BK) {
        __syncthreads();
        gll16(Ah + aoff0 + k0, lA0);
        gll16(Ah + aoff1 + k0, lA1);
        gll16(Bh + boff0 + k0, lB0);
        gll16(Bh + boff1 + k0, lB1);
        if (SPLIT) {
            gll16(Al + aoff0 + k0, lA0l);
            gll16(Al + aoff1 + k0, lA1l);
            gll16(Bl + boff0 + k0, lB0l);
            gll16(Bl + boff1 + k0, lB1l);
        }
        __syncthreads();

        short8 a_h[4], b_h[4], a_l[4], b_l[4];
#pragma unroll
        for (int mi = 0; mi < 4; ++mi) {
            int r = wm + mi * 16 + l15;
            int off = r * BK + (((quad ^ (r >> 1)) & 3) << 3);
            a_h[mi] = *(const short8*)&As_h[off];
            if (SPLIT) a_l[mi] = *(const short8*)&As_l[off];
        }
#pragma unroll
        for (int ni = 0; ni < 4; ++ni) {
            int r = wn + ni * 16 + l15;
            int off = r * BK + (((quad ^ (r >> 1)) & 3) << 3);
            b_h[ni] = *(const short8*)&Bs_h[off];
            if (SPLIT) b_l[ni] = *(const short8*)&Bs_l[off];
        }
#pragma unroll
        for (int mi = 0; mi < 4; ++mi)
#pragma unroll
            for (int ni = 0; ni < 4; ++ni) {
                acc[mi][ni] = __builtin_amdgcn_mfma_f32_16x16x32_bf16(
                    a_h[mi], b_h[ni], acc[mi][ni], 0, 0, 0);
                if (SPLIT) {
                    acc[mi][ni] = __builtin_amdgcn_mfma_f32_16x16x32_bf16(
                        a_h[mi], b_l[ni], acc[mi][ni], 0, 0, 0);
                    acc[mi][ni] = __builtin_amdgcn_mfma_f32_16x16x32_bf16(
                        a_l[mi], b_h[ni], acc[mi][ni], 0, 0, 0);
                }
            }
    }

    // epilogue: C/D layout col=lane&15, row=quad*4+reg  [verified m89/m91]
#pragma unroll
    for (int mi = 0; mi < 4; ++mi)
#pragma unroll
        for (int ni = 0; ni < 4; ++ni) {
            int colg = n0 + wn + ni * 16 + l15;
            float bv = bias ? bias[colg] : 0.f;
#pragma unroll
            for (int r = 0; r < 4; ++r) {
                int rowg = m0 + wm + mi * 16 + quad * 4 + r;
                float v = acc[mi][ni][r] + bv;
                long long idx = zC + (long long)rowg * N + colg;
                if (mode == 0) {
                    Cf[idx] = v;
                } else if (mode == 1) {
                    unsigned short h = f2bf(v);
                    Chi[idx] = h;
                    Clo[idx] = f2bf(v - bf2f(h));
                } else {
                    Chi[idx] = f2bf(v);
                }
            }
        }
}

// ---------------------------------------------------------------------------
// row softmax: S [rows][cols] fp32 -> P bf16.  One block per row, cols=2048.
// ---------------------------------------------------------------------------
__global__ __launch_bounds__(256)
void softmax_rows(const float* __restrict__ S, unsigned short* __restrict__ P,
                  int cols) {
    __shared__ float red_m[4];
    __shared__ float red_s[4];
    const long long row = blockIdx.x;
    const float* s = S + row * cols;
    unsigned short* p = P + row * cols;
    const int tid = threadIdx.x;
    const int lane = tid & 63;
    const int wave = tid >> 6;

    float4 v0 = *(const float4*)(s + tid * 8);
    float4 v1 = *(const float4*)(s + tid * 8 + 4);
    float vals[8] = {v0.x, v0.y, v0.z, v0.w, v1.x, v1.y, v1.z, v1.w};

    float m = vals[0];
#pragma unroll
    for (int i = 1; i < 8; ++i) m = fmaxf(m, vals[i]);
#pragma unroll
    for (int off = 32; off >= 1; off >>= 1) m = fmaxf(m, __shfl_xor(m, off));
    if (lane == 0) red_m[wave] = m;
    __syncthreads();
    m = fmaxf(fmaxf(red_m[0], red_m[1]), fmaxf(red_m[2], red_m[3]));

    float e[8];
    float sum = 0.f;
#pragma unroll
    for (int i = 0; i < 8; ++i) {
        e[i] = __expf(vals[i] - m);
        sum += e[i];
    }
#pragma unroll
    for (int off = 32; off >= 1; off >>= 1) sum += __shfl_xor(sum, off);
    if (lane == 0) red_s[wave] = sum;
    __syncthreads();
    sum = red_s[0] + red_s[1] + red_s[2] + red_s[3];
    float inv = 1.0f / sum;

    unsigned short ob[8];
#pragma unroll
    for (int i = 0; i < 8; ++i) ob[i] = f2bf(e[i] * inv);
    *(ushort4*)(p + tid * 8)     = make_ushort4(ob[0], ob[1], ob[2], ob[3]);
    *(ushort4*)(p + tid * 8 + 4) = make_ushort4(ob[4], ob[5], ob[6], ob[7]);
}

// ---------------------------------------------------------------------------
extern "C" void kernel_launch(void* const* d_in, const int* in_sizes, int n_in,
                              void* d_out, int out_size, void* d_ws,
                              size_t ws_size, hipStream_t stream) {
    const float* x  = (const float*)d_in[0];
    const float* Wk = (const float*)d_in[1];
    const float* bk = (const float*)d_in[2];
    const float* Wq = (const float*)d_in[3];
    const float* bq = (const float*)d_in[4];
    const float* Wv = (const float*)d_in[5];
    const float* bv = (const float*)d_in[6];
    float* out = (float*)d_out;

    const int Bb = 4, Ns = 2048, E = 1024, Aa = 1024;
    const int M = Bb * Ns;  // 8192

    char* p = (char*)d_ws;
    auto alloc = [&](size_t bytes) {
        char* r = p;
        p += (bytes + 255) & ~(size_t)255;
        return r;
    };
    const size_t MA = (size_t)M * Aa;          // 8.39M elems
    unsigned short* xh = (unsigned short*)alloc(MA * 2);
    unsigned short* xl = (unsigned short*)alloc(MA * 2);
    unsigned short* Wth[3], *Wtl[3];
    for (int i = 0; i < 3; ++i) {
        Wth[i] = (unsigned short*)alloc((size_t)E * Aa * 2);
        Wtl[i] = (unsigned short*)alloc((size_t)E * Aa * 2);
    }
    unsigned short* kh = (unsigned short*)alloc(MA * 2);
    unsigned short* kl = (unsigned short*)alloc(MA * 2);
    unsigned short* qh = (unsigned short*)alloc(MA * 2);
    unsigned short* ql = (unsigned short*)alloc(MA * 2);
    unsigned short* vbf = (unsigned short*)alloc(MA * 2);
    unsigned short* vT  = (unsigned short*)alloc(MA * 2);
    float* scores = (float*)alloc((size_t)Bb * Ns * Ns * 4);
    // attn (bf16, 33.5MB) overlays the dead x_hi/x_lo region (33.5MB)
    unsigned short* attn = xh;

    // 1. split x, W (W transposed so B-operand has contiguous K)
    split_f32<<<(int)(MA / 4 / 256), 256, 0, stream>>>(x, xh, xl, (int)MA);
    splitT_w<<<dim3(Aa / 32, E / 32), 256, 0, stream>>>(Wk, Wth[0], Wtl[0], E, Aa);
    splitT_w<<<dim3(Aa / 32, E / 32), 256, 0, stream>>>(Wq, Wth[1], Wtl[1], E, Aa);
    splitT_w<<<dim3(Aa / 32, E / 32), 256, 0, stream>>>(Wv, Wth[2], Wtl[2], E, Aa);

    // 2. projections (3-term split for k/q; 1-term for v -- it feeds a bf16
    //    GEMM anyway, so split accuracy is wasted there)
    dim3 g1(Aa / TILE, M / TILE, 1);
    gemm_nt<true><<<g1, 256, 0, stream>>>(xh, xl, Wth[0], Wtl[0], bk, nullptr,
                                          kh, kl, 1, M, Aa, E, 0, 0, 0);
    gemm_nt<true><<<g1, 256, 0, stream>>>(xh, xl, Wth[1], Wtl[1], bq, nullptr,
                                          qh, ql, 1, M, Aa, E, 0, 0, 0);
    gemm_nt<false><<<g1, 256, 0, stream>>>(xh, nullptr, Wth[2], nullptr, bv,
                                           nullptr, vbf, nullptr, 2, M, Aa, E,
                                           0, 0, 0);

    // 3. scores[b,n,m] = k[b,n,:] . q[b,m,:]   (batched NT, fp32 out)
    dim3 g2(Ns / TILE, Ns / TILE, Bb);
    gemm_nt<true><<<g2, 256, 0, stream>>>(
        kh, kl, qh, ql, nullptr, scores, nullptr, nullptr, 0, Ns, Ns, Aa,
        (long long)Ns * Aa, (long long)Ns * Aa, (long long)Ns * Ns);

    // 4. softmax rows -> bf16 attn
    softmax_rows<<<M, 256, 0, stream>>>(scores, attn, Ns);

    // 5. v -> v^T (so attn@v is NT with contiguous K=m)
    transpose_bf<<<dim3(Aa / 32, Ns / 32, Bb), 256, 0, stream>>>(vbf, vT, Ns, Aa);

    // 6. out[b,n,a] = sum_m attn[b,n,m] * vT[b,a,m]
    dim3 g3(Aa / TILE, Ns / TILE, Bb);
    gemm_nt<false><<<g3, 256, 0, stream>>>(
        attn, nullptr, vT, nullptr, nullptr, out, nullptr, nullptr, 0, Ns, Aa,
        Ns, (long long)Ns * Ns, (long long)Aa * Ns, (long long)Ns * Aa);
}

// Round 3
// 400.575 us; speedup vs baseline: 1.3384x; 1.1772x over previous
//
#include <hip/hip_runtime.h>

// ---------------------------------------------------------------------------
// SelfAttention: out = softmax((x@Wk+bk) @ (x@Wq+bq)^T) @ (x@Wv+bv)
// B=4, N=2048, E=A=1024, fp32 in/out.
// R3 numerics plan:
//   k/q projections: bf16x2 3-term split (error ~2^-17) -> round k,q to fp16
//   scores:          1-term fp16 MFMA (score err ~0.011 abs vs sigma=32)
//   v proj, attn, PV: all fp16 (8x finer than bf16, same MFMA rate)
// ---------------------------------------------------------------------------

typedef __attribute__((ext_vector_type(8))) short short8;      // 8x16b = 4 VGPRs
typedef __attribute__((ext_vector_type(8))) _Float16 half8;
typedef __attribute__((ext_vector_type(4))) float floatx4;

#define TILE 128
#define BK 32

static __device__ __forceinline__ unsigned short f2bf(float f) {
    unsigned int u = __float_as_uint(f);
    u += 0x7FFFu + ((u >> 16) & 1u);   // round-to-nearest-even
    return (unsigned short)(u >> 16);
}
static __device__ __forceinline__ float bf2f(unsigned short h) {
    return __uint_as_float(((unsigned int)h) << 16);
}
static __device__ __forceinline__ unsigned short f2h(float f) {
    _Float16 h = (_Float16)f;          // RNE
    return *(unsigned short*)&h;
}

// async global->LDS, 16B per lane; LDS dst = wave-uniform base + lane*16
static __device__ __forceinline__ void gll16(const unsigned short* g,
                                             unsigned short* l) {
    __builtin_amdgcn_global_load_lds(
        (__attribute__((address_space(1))) void*)(g),
        (__attribute__((address_space(3))) void*)(l), 16, 0, 0);
}

// ---------------------------------------------------------------------------
// split fp32 -> bf16 hi + bf16 lo + fp16 single (elementwise, n % 4 == 0)
// ---------------------------------------------------------------------------
__global__ void split_f32(const float* __restrict__ src,
                          unsigned short* __restrict__ hi,
                          unsigned short* __restrict__ lo,
                          unsigned short* __restrict__ h16, int n) {
    int i = (blockIdx.x * blockDim.x + threadIdx.x) * 4;
    if (i >= n) return;
    float4 f = *(const float4*)(src + i);
    float v[4] = {f.x, f.y, f.z, f.w};
    unsigned short hh[4], ll[4], xx[4];
#pragma unroll
    for (int j = 0; j < 4; ++j) {
        hh[j] = f2bf(v[j]);
        ll[j] = f2bf(v[j] - bf2f(hh[j]));
        xx[j] = f2h(v[j]);
    }
    *(ushort4*)(hi + i)  = make_ushort4(hh[0], hh[1], hh[2], hh[3]);
    *(ushort4*)(lo + i)  = make_ushort4(ll[0], ll[1], ll[2], ll[3]);
    *(ushort4*)(h16 + i) = make_ushort4(xx[0], xx[1], xx[2], xx[3]);
}

// ---------------------------------------------------------------------------
// W [R][C] fp32 -> W^T [C][R]; fmt 0: bf16 hi/lo into Th/Tl, fmt 1: fp16 -> Th
// ---------------------------------------------------------------------------
__global__ void splitT_w(const float* __restrict__ W,
                         unsigned short* __restrict__ Th,
                         unsigned short* __restrict__ Tl, int R, int C,
                         int fmt) {
    __shared__ float tile[32][33];
    int tx = threadIdx.x & 31, ty = threadIdx.x >> 5;   // 32 x 8
    int c0 = blockIdx.x * 32, r0 = blockIdx.y * 32;
#pragma unroll
    for (int j = 0; j < 32; j += 8)
        tile[ty + j][tx] = W[(long long)(r0 + ty + j) * C + c0 + tx];
    __syncthreads();
#pragma unroll
    for (int j = 0; j < 32; j += 8) {
        float v = tile[tx][ty + j];                      // = W[r0+tx][c0+ty+j]
        long long idx = (long long)(c0 + ty + j) * R + r0 + tx;
        if (fmt == 0) {
            unsigned short h = f2bf(v);
            Th[idx] = h;
            Tl[idx] = f2bf(v - bf2f(h));
        } else {
            Th[idx] = f2h(v);
        }
    }
}

// ---------------------------------------------------------------------------
// 16-bit transpose: src [z][R][C] -> dst [z][C][R]
// ---------------------------------------------------------------------------
__global__ void transpose_bf(const unsigned short* __restrict__ src,
                             unsigned short* __restrict__ dst, int R, int C) {
    __shared__ unsigned short tile[32][33];
    long long zs = (long long)blockIdx.z * R * C;
    int tx = threadIdx.x & 31, ty = threadIdx.x >> 5;
    int c0 = blockIdx.x * 32, r0 = blockIdx.y * 32;
#pragma unroll
    for (int j = 0; j < 32; j += 8)
        tile[ty + j][tx] = src[zs + (long long)(r0 + ty + j) * C + c0 + tx];
    __syncthreads();
#pragma unroll
    for (int j = 0; j < 32; j += 8)
        dst[zs + (long long)(c0 + ty + j) * R + r0 + tx] = tile[tx][ty + j];
}

// ---------------------------------------------------------------------------
// NT GEMM: C[M,N] = A[M,K] * B[N,K]^T (+bias[col]); fp32 acc.
// SPLIT (bf16): A=Ah+Al, B=Bh+Bl, 3-term product (drops lo*lo).
// F16: single-term fp16 MFMA.
// mode 0: fp32 -> Cf; mode 3: fp16 -> Chi.
// LDS: unpadded [row][32] tiles (global_load_lds requirement); bank conflicts
// broken by XOR chunk swizzle (symmetric at stage and ds_read time).
// ---------------------------------------------------------------------------
template <bool SPLIT, bool F16>
__global__ __launch_bounds__(256)
void gemm_nt(const unsigned short* __restrict__ Ah,
             const unsigned short* __restrict__ Al,
             const unsigned short* __restrict__ Bh,
             const unsigned short* __restrict__ Bl,
             const float* __restrict__ bias,
             float* __restrict__ Cf,
             unsigned short* __restrict__ Chi,
             int mode, int M, int N, int K,
             long long sA, long long sB, long long sC) {
    __shared__ unsigned short smem[(SPLIT ? 4 : 2) * TILE * BK];
    unsigned short* As_h = smem;
    unsigned short* Bs_h = smem + TILE * BK;
    unsigned short* As_l = SPLIT ? smem + 2 * TILE * BK : smem;
    unsigned short* Bs_l = SPLIT ? smem + 3 * TILE * BK : smem;

    const int tid = threadIdx.x;
    const int lane = tid & 63;
    const int wave = tid >> 6;
    const int quad = lane >> 4;
    const int l15 = lane & 15;
    const int wm = (wave & 1) * 64;
    const int wn = (wave >> 1) * 64;

    const long long zA = (long long)blockIdx.z * sA;
    const long long zB = (long long)blockIdx.z * sB;
    const long long zC = (long long)blockIdx.z * sC;
    const int m0 = blockIdx.y * TILE;
    const int n0 = blockIdx.x * TILE;

    // wave w stages rows [32w, 32w+32); lane i covers row (i>>2),
    // global chunk c = (i&3) ^ ((i>>3)&3)  [XOR swizzle]
    const int srow = wave * 32 + (lane >> 2);
    const int schunk8 = (((lane & 3) ^ ((lane >> 3) & 3)) << 3);
    const long long aoff0 = zA + (long long)(m0 + srow) * K + schunk8;
    const long long boff0 = zB + (long long)(n0 + srow) * K + schunk8;
    const long long aoff1 = aoff0 + 16LL * K;
    const long long boff1 = boff0 + 16LL * K;
    unsigned short* lA0 = As_h + (wave * 32) * BK;
    unsigned short* lA1 = lA0 + 16 * BK;
    unsigned short* lB0 = Bs_h + (wave * 32) * BK;
    unsigned short* lB1 = lB0 + 16 * BK;
    unsigned short* lA0l = As_l + (wave * 32) * BK;
    unsigned short* lA1l = lA0l + 16 * BK;
    unsigned short* lB0l = Bs_l + (wave * 32) * BK;
    unsigned short* lB1l = lB0l + 16 * BK;

    floatx4 zero = {0.f, 0.f, 0.f, 0.f};
    floatx4 acc[4][4];
#pragma unroll
    for (int i = 0; i < 4; ++i)
#pragma unroll
        for (int j = 0; j < 4; ++j) acc[i][j] = zero;

    for (int k0 = 0; k0 < K; k0 += BK) {
        __syncthreads();
        gll16(Ah + aoff0 + k0, lA0);
        gll16(Ah + aoff1 + k0, lA1);
        gll16(Bh + boff0 + k0, lB0);
        gll16(Bh + boff1 + k0, lB1);
        if (SPLIT) {
            gll16(Al + aoff0 + k0, lA0l);
            gll16(Al + aoff1 + k0, lA1l);
            gll16(Bl + boff0 + k0, lB0l);
            gll16(Bl + boff1 + k0, lB1l);
        }
        __syncthreads();

        short8 a_h[4], b_h[4], a_l[4], b_l[4];
#pragma unroll
        for (int mi = 0; mi < 4; ++mi) {
            int r = wm + mi * 16 + l15;
            int off = r * BK + (((quad ^ (r >> 1)) & 3) << 3);
            a_h[mi] = *(const short8*)&As_h[off];
            if (SPLIT) a_l[mi] = *(const short8*)&As_l[off];
        }
#pragma unroll
        for (int ni = 0; ni < 4; ++ni) {
            int r = wn + ni * 16 + l15;
            int off = r * BK + (((quad ^ (r >> 1)) & 3) << 3);
            b_h[ni] = *(const short8*)&Bs_h[off];
            if (SPLIT) b_l[ni] = *(const short8*)&Bs_l[off];
        }
#pragma unroll
        for (int mi = 0; mi < 4; ++mi)
#pragma unroll
            for (int ni = 0; ni < 4; ++ni) {
                if (F16) {
                    acc[mi][ni] = __builtin_amdgcn_mfma_f32_16x16x32_f16(
                        *(const half8*)&a_h[mi], *(const half8*)&b_h[ni],
                        acc[mi][ni], 0, 0, 0);
                } else {
                    acc[mi][ni] = __builtin_amdgcn_mfma_f32_16x16x32_bf16(
                        a_h[mi], b_h[ni], acc[mi][ni], 0, 0, 0);
                    if (SPLIT) {
                        acc[mi][ni] = __builtin_amdgcn_mfma_f32_16x16x32_bf16(
                            a_h[mi], b_l[ni], acc[mi][ni], 0, 0, 0);
                        acc[mi][ni] = __builtin_amdgcn_mfma_f32_16x16x32_bf16(
                            a_l[mi], b_h[ni], acc[mi][ni], 0, 0, 0);
                    }
                }
            }
    }

    // epilogue: C/D layout col=lane&15, row=quad*4+reg  [verified m89/m91]
#pragma unroll
    for (int mi = 0; mi < 4; ++mi)
#pragma unroll
        for (int ni = 0; ni < 4; ++ni) {
            int colg = n0 + wn + ni * 16 + l15;
            float bv = bias ? bias[colg] : 0.f;
#pragma unroll
            for (int r = 0; r < 4; ++r) {
                int rowg = m0 + wm + mi * 16 + quad * 4 + r;
                float v = acc[mi][ni][r] + bv;
                long long idx = zC + (long long)rowg * N + colg;
                if (mode == 0) Cf[idx] = v;
                else           Chi[idx] = f2h(v);
            }
        }
}

// ---------------------------------------------------------------------------
// row softmax: S [rows][cols] fp32 -> P fp16.  One block per row, cols=2048.
// ---------------------------------------------------------------------------
__global__ __launch_bounds__(256)
void softmax_rows(const float* __restrict__ S, unsigned short* __restrict__ P,
                  int cols) {
    __shared__ float red_m[4];
    __shared__ float red_s[4];
    const long long row = blockIdx.x;
    const float* s = S + row * cols;
    unsigned short* p = P + row * cols;
    const int tid = threadIdx.x;
    const int lane = tid & 63;
    const int wave = tid >> 6;

    float4 v0 = *(const float4*)(s + tid * 8);
    float4 v1 = *(const float4*)(s + tid * 8 + 4);
    float vals[8] = {v0.x, v0.y, v0.z, v0.w, v1.x, v1.y, v1.z, v1.w};

    float m = vals[0];
#pragma unroll
    for (int i = 1; i < 8; ++i) m = fmaxf(m, vals[i]);
#pragma unroll
    for (int off = 32; off >= 1; off >>= 1) m = fmaxf(m, __shfl_xor(m, off));
    if (lane == 0) red_m[wave] = m;
    __syncthreads();
    m = fmaxf(fmaxf(red_m[0], red_m[1]), fmaxf(red_m[2], red_m[3]));

    float e[8];
    float sum = 0.f;
#pragma unroll
    for (int i = 0; i < 8; ++i) {
        e[i] = __expf(vals[i] - m);
        sum += e[i];
    }
#pragma unroll
    for (int off = 32; off >= 1; off >>= 1) sum += __shfl_xor(sum, off);
    if (lane == 0) red_s[wave] = sum;
    __syncthreads();
    sum = red_s[0] + red_s[1] + red_s[2] + red_s[3];
    float inv = 1.0f / sum;

    unsigned short ob[8];
#pragma unroll
    for (int i = 0; i < 8; ++i) ob[i] = f2h(e[i] * inv);
    *(ushort4*)(p + tid * 8)     = make_ushort4(ob[0], ob[1], ob[2], ob[3]);
    *(ushort4*)(p + tid * 8 + 4) = make_ushort4(ob[4], ob[5], ob[6], ob[7]);
}

// ---------------------------------------------------------------------------
extern "C" void kernel_launch(void* const* d_in, const int* in_sizes, int n_in,
                              void* d_out, int out_size, void* d_ws,
                              size_t ws_size, hipStream_t stream) {
    const float* x  = (const float*)d_in[0];
    const float* Wk = (const float*)d_in[1];
    const float* bk = (const float*)d_in[2];
    const float* Wq = (const float*)d_in[3];
    const float* bq = (const float*)d_in[4];
    const float* Wv = (const float*)d_in[5];
    const float* bv = (const float*)d_in[6];
    float* out = (float*)d_out;

    const int Bb = 4, Ns = 2048, E = 1024, Aa = 1024;
    const int M = Bb * Ns;  // 8192

    char* p = (char*)d_ws;
    auto alloc = [&](size_t bytes) {
        char* r = p;
        p += (bytes + 255) & ~(size_t)255;
        return r;
    };
    const size_t MA = (size_t)M * Aa;          // 8.39M elems
    unsigned short* xh  = (unsigned short*)alloc(MA * 2);
    unsigned short* xl  = (unsigned short*)alloc(MA * 2);
    unsigned short* x16 = (unsigned short*)alloc(MA * 2);
    unsigned short* Wth[3], *Wtl[3];
    for (int i = 0; i < 3; ++i) {
        Wth[i] = (unsigned short*)alloc((size_t)E * Aa * 2);
        Wtl[i] = (unsigned short*)alloc((size_t)E * Aa * 2);
    }
    unsigned short* k16 = (unsigned short*)alloc(MA * 2);
    unsigned short* q16 = (unsigned short*)alloc(MA * 2);
    unsigned short* v16 = (unsigned short*)alloc(MA * 2);
    unsigned short* vT  = (unsigned short*)alloc(MA * 2);
    float* scores = (float*)alloc((size_t)Bb * Ns * Ns * 4);
    // attn (fp16, 33.5MB) overlays the dead x_hi region
    unsigned short* attn = xh;

    // 1. split x -> bf16 hi/lo + fp16; W^T: bf16 split for Wk/Wq, fp16 for Wv
    split_f32<<<(int)(MA / 4 / 256), 256, 0, stream>>>(x, xh, xl, x16, (int)MA);
    splitT_w<<<dim3(Aa / 32, E / 32), 256, 0, stream>>>(Wk, Wth[0], Wtl[0], E, Aa, 0);
    splitT_w<<<dim3(Aa / 32, E / 32), 256, 0, stream>>>(Wq, Wth[1], Wtl[1], E, Aa, 0);
    splitT_w<<<dim3(Aa / 32, E / 32), 256, 0, stream>>>(Wv, Wth[2], Wtl[2], E, Aa, 1);

    // 2. projections: k/q 3-term bf16 split -> fp16 out; v 1-term fp16
    dim3 g1(Aa / TILE, M / TILE, 1);
    gemm_nt<true, false><<<g1, 256, 0, stream>>>(xh, xl, Wth[0], Wtl[0], bk,
                                                 nullptr, k16, 3, M, Aa, E, 0, 0, 0);
    gemm_nt<true, false><<<g1, 256, 0, stream>>>(xh, xl, Wth[1], Wtl[1], bq,
                                                 nullptr, q16, 3, M, Aa, E, 0, 0, 0);
    gemm_nt<false, true><<<g1, 256, 0, stream>>>(x16, nullptr, Wth[2], nullptr, bv,
                                                 nullptr, v16, 3, M, Aa, E, 0, 0, 0);

    // 3. scores[b,n,m] = k[b,n,:] . q[b,m,:]   (batched NT fp16, fp32 out)
    dim3 g2(Ns / TILE, Ns / TILE, Bb);
    gemm_nt<false, true><<<g2, 256, 0, stream>>>(
        k16, nullptr, q16, nullptr, nullptr, scores, nullptr, 0, Ns, Ns, Aa,
        (long long)Ns * Aa, (long long)Ns * Aa, (long long)Ns * Ns);

    // 4. softmax rows -> fp16 attn
    softmax_rows<<<M, 256, 0, stream>>>(scores, attn, Ns);

    // 5. v -> v^T (so attn@v is NT with contiguous K=m)
    transpose_bf<<<dim3(Aa / 32, Ns / 32, Bb), 256, 0, stream>>>(v16, vT, Ns, Aa);

    // 6. out[b,n,a] = sum_m attn[b,n,m] * vT[b,a,m]
    dim3 g3(Aa / TILE, Ns / TILE, Bb);
    gemm_nt<false, true><<<g3, 256, 0, stream>>>(
        attn, nullptr, vT, nullptr, nullptr, out, nullptr, 0, Ns, Aa, Ns,
        (long long)Ns * Ns, (long long)Aa * Ns, (long long)Ns * Aa);
}